// Round 1
// baseline (411.084 us; speedup 1.0000x reference)
//
#include <hip/hip_runtime.h>

// FullScan: y[k,t] layout (K=8 rows of L=1e6), fp32.
//  left  j in [0,31):  out[k*L+j]          = sum_{m=0}^{32+j} sum_d x[d,m]*P[k,d,m]
//  mid   t in [0,NMID): out[k*L+31+t]      = sum_{d,w} x[d,t+w]*P[k,d,w]
//  right j in [0,32):  out[k*L+999968+j]   = sum_{m=j+1}^{63} sum_d x[d,L-W+m]*P[k,d,m]

constexpr int D    = 16;
constexpr int L    = 1000000;
constexpr int W    = 64;
constexpr int K    = 8;
constexpr int PADL = (W - 1) / 2;      // 31
constexpr int NMID = L - W + 1;        // 999937
constexpr int TPB  = 256;
constexpr int RPT  = 2;                // outputs per thread
constexpr int TILE = TPB * RPT;        // 512 positions per block
constexpr int HALO = W - 1;            // 63
constexpr int XCOLS = TILE + HALO;     // 575

__global__ __launch_bounds__(TPB) void fullscan_mid(
    const float* __restrict__ x, const float* __restrict__ P,
    float* __restrict__ out)
{
    __shared__ float xs[D][XCOLS];
    const int t0 = blockIdx.x * TILE;

    // Stage x tile: coalesced row-by-row, zero-fill past L (outputs there are
    // never stored).
    for (int d = 0; d < D; ++d) {
        for (int i = threadIdx.x; i < XCOLS; i += TPB) {
            const int g = t0 + i;
            xs[d][i] = (g < L) ? x[d * L + g] : 0.0f;
        }
    }
    __syncthreads();

    float acc[RPT][K];
#pragma unroll
    for (int r = 0; r < RPT; ++r)
#pragma unroll
        for (int k = 0; k < K; ++k) acc[r][k] = 0.0f;

    const int toff = threadIdx.x * RPT;

    // d kept as a rolled loop (body ~1k instrs; unrolling 16x would blow I$).
#pragma unroll 1
    for (int d = 0; d < D; ++d) {
        // 65-float register window: x[d, t0+toff .. t0+toff+64]
        float xw[W + RPT - 1];
#pragma unroll
        for (int j = 0; j < W + RPT - 1; ++j) xw[j] = xs[d][toff + j];

#pragma unroll
        for (int k = 0; k < K; ++k) {
            const float* __restrict__ Pkd = P + (k * D + d) * W;
            // Wave-uniform P index -> s_load_dwordx16 bursts; FMA reads SGPR.
#pragma unroll
            for (int w = 0; w < W; ++w) {
                const float p = Pkd[w];
#pragma unroll
                for (int r = 0; r < RPT; ++r)
                    acc[r][k] = fmaf(xw[w + r], p, acc[r][k]);
            }
        }
    }

#pragma unroll
    for (int r = 0; r < RPT; ++r) {
        const int t = t0 + toff + r;
        if (t < NMID) {
#pragma unroll
            for (int k = 0; k < K; ++k)
                out[k * L + PADL + t] = acc[r][k];
        }
    }
}

// 63 edge outputs per k (31 left + 32 right), one small block.
__global__ void fullscan_edge(
    const float* __restrict__ x, const float* __restrict__ P,
    float* __restrict__ out)
{
    const int tid = threadIdx.x;          // 512 threads
    const int k = tid >> 6;
    const int j = tid & 63;
    if (k >= K) return;

    if (j < PADL) {
        // left[k,j] = sum_{m=0}^{32+j} sum_d x[d,m]*P[k,d,m]
        float acc = 0.0f;
        for (int m = 0; m <= (W - PADL - 1) + j; ++m) {
#pragma unroll
            for (int d = 0; d < D; ++d)
                acc = fmaf(x[d * L + m], P[(k * D + d) * W + m], acc);
        }
        out[k * L + j] = acc;
    } else if (j < 2 * PADL + 1) {
        // right[k,jj] = sum_{m=jj+1}^{63} sum_d x[d,L-W+m]*P[k,d,m]
        const int jj = j - PADL;          // 0..31
        float acc = 0.0f;
        for (int m = jj + 1; m < W; ++m) {
#pragma unroll
            for (int d = 0; d < D; ++d)
                acc = fmaf(x[d * L + (L - W) + m], P[(k * D + d) * W + m], acc);
        }
        out[k * L + PADL + NMID + jj] = acc;
    }
}

extern "C" void kernel_launch(void* const* d_in, const int* in_sizes, int n_in,
                              void* d_out, int out_size, void* d_ws, size_t ws_size,
                              hipStream_t stream)
{
    const float* x = (const float*)d_in[0];   // (D, L)
    const float* P = (const float*)d_in[1];   // (K, D, W)
    float* out = (float*)d_out;               // (K*L, 1)

    const int nblocks = (NMID + TILE - 1) / TILE;   // 1954
    hipLaunchKernelGGL(fullscan_mid, dim3(nblocks), dim3(TPB), 0, stream, x, P, out);
    hipLaunchKernelGGL(fullscan_edge, dim3(1), dim3(512), 0, stream, x, P, out);
}

// Round 2
// 207.847 us; speedup vs baseline: 1.9778x; 1.9778x over previous
//
#include <hip/hip_runtime.h>

// FullScan via bf16 MFMA (16x16x32).
// out[k,t] = sum_{d<16,w<64} x[d,t+w] * P[k,d,w], K=8 channels, L=1e6.
// MFMA mapping: M rows 0..7 = P taps w<32 (lo), rows 8..15 = P taps w>=32 (hi).
//   D_lo[k](s) = sum_{w<32} P[k,d,w]    x[d,s+w]
//   D_hi[k](s) = sum_{w<32} P[k,d,32+w] x[d,s+w]
//   out[k,t]   = D_lo[k](t) + D_hi[k](t+32)   (combine 2 n-tiles apart)
// Reduction chunk c (16 per position-tile): r = (w-2c)*16 + d, w in {2c,2c+1}.
// Lane l: n=l&15, q=l>>4. A/B frag element j (0..7): r = 8q+j ->
//   w = 2c + (q>>1), d = 8*(q&1)+j  => 8 contiguous d => aligned b128 reads
//   from d-major LDS tile xs[pos][16], XOR-swizzled on bit4 by (pos>>2)&1.

constexpr int D    = 16;
constexpr int L    = 1000000;
constexpr int W    = 64;
constexpr int K    = 8;
constexpr int PADL = 31;
constexpr int NMID = L - W + 1;        // 999937
constexpr int TPB  = 256;              // 4 waves
constexpr int OUT_TILES = 30;          // 16-pos output tiles per block
constexpr int BLK_OUT   = OUT_TILES * 16;   // 480
constexpr int XS   = 544;              // staged x positions (computes 32 tiles)
constexpr int NBLK = (NMID + BLK_OUT - 1) / BLK_OUT;  // 2084

typedef __attribute__((ext_vector_type(8))) short short8;
typedef __attribute__((ext_vector_type(4))) float floatx4;

__device__ __forceinline__ unsigned short f2bf(float f) {
    union { float f; unsigned u; } v; v.f = f;
    unsigned u = v.u + 0x7fff + ((v.u >> 16) & 1);   // RNE
    return (unsigned short)(u >> 16);
}

__global__ __launch_bounds__(TPB, 3) void fullscan_mid(
    const float* __restrict__ x, const unsigned short* __restrict__ afr,
    float* __restrict__ out)
{
    __shared__ __align__(16) unsigned short xs[XS * 16];
    __shared__ float hibuf[6][8][16];   // bounced hi-rows: waves 1..3, tiles 0,1

    const int s0  = blockIdx.x * BLK_OUT;
    const int tid = threadIdx.x;

    // Stage x tile: global-coalesced per d-row, d-major (swizzled) in LDS.
    for (int d = 0; d < D; ++d) {
        const float* xr = x + d * L + s0;
        for (int i = tid; i < XS; i += TPB) {
            const int g = s0 + i;
            const float v = (g < L) ? xr[i] : 0.0f;
            xs[i * 16 + ((((d >> 3) ^ ((i >> 2) & 1)) << 3) | (d & 7))] = f2bf(v);
        }
    }

    const int lane = tid & 63;
    const int wv   = tid >> 6;
    const int n    = lane & 15;
    const int q    = lane >> 4;

    // Resident A fragments (P), coalesced from the prep table.
    short8 A[16];
#pragma unroll
    for (int c = 0; c < 16; ++c)
        A[c] = *(const short8*)(afr + (c * 64 + lane) * 8);

    __syncthreads();

    floatx4 acc[8];
#pragma unroll
    for (int j = 0; j < 8; ++j) acc[j] = (floatx4){0.f, 0.f, 0.f, 0.f};

    const int pbase = wv * 128 + n + (q >> 1);
    const int half  = q & 1;

#pragma unroll
    for (int c = 0; c < 16; ++c) {
        short8 B[8];
#pragma unroll
        for (int j = 0; j < 8; ++j) {
            const int pos = pbase + j * 16 + 2 * c;
            B[j] = *(const short8*)(&xs[pos * 16 + ((half ^ ((pos >> 2) & 1)) << 3)]);
        }
#pragma unroll
        for (int j = 0; j < 8; ++j)
            acc[j] = __builtin_amdgcn_mfma_f32_16x16x32_bf16(A[c], B[j], acc[j], 0, 0, 0);
    }

    // Bounce hi-rows of each wave's first two tiles for the previous wave.
    if (wv >= 1 && q >= 2) {
#pragma unroll
        for (int jj = 0; jj < 2; ++jj)
#pragma unroll
            for (int r = 0; r < 4; ++r)
                hibuf[(wv - 1) * 2 + jj][(q - 2) * 4 + r][n] = acc[jj][r];
    }
    __syncthreads();

    // Combine lo + shifted hi and store. Wave w outputs tiles 8w..(8w+5|7).
    const int nout = (wv < 3) ? 8 : 6;
#pragma unroll
    for (int jj = 0; jj < 8; ++jj) {
        if (jj >= nout) break;
        float res[4];
        if (jj < 6) {
#pragma unroll
            for (int r = 0; r < 4; ++r) {
                const float hi = __shfl(acc[jj + 2][r], lane | 32, 64);
                res[r] = acc[jj][r] + hi;
            }
        } else if (q < 2) {
#pragma unroll
            for (int r = 0; r < 4; ++r)
                res[r] = acc[jj][r] + hibuf[wv * 2 + (jj - 6)][q * 4 + r][n];
        }
        if (q < 2) {
            const int t = s0 + (wv * 8 + jj) * 16 + n;
            if (t < NMID) {
#pragma unroll
                for (int r = 0; r < 4; ++r)
                    out[(q * 4 + r) * L + PADL + t] = res[r];
            }
        }
    }
}

// Prep: build A-fragment table (bf16) in ws + compute the 63 edge outputs per k.
__global__ void fullscan_prep(
    const float* __restrict__ x, const float* __restrict__ P,
    unsigned short* __restrict__ afr, float* __restrict__ out)
{
    const int tid = threadIdx.x;   // 512 threads, 1 block

    // A-frag table: afr[c*512 + lane*8 + j]
    for (int u = tid; u < 16 * 64 * 8; u += 512) {
        const int c = u >> 9, lane = (u >> 3) & 63, j = u & 7;
        const int m = lane & 15, qq = lane >> 4;
        const int k = m & 7, half = m >> 3;
        const int w = half * 32 + 2 * c + (qq >> 1);
        const int d = ((qq & 1) << 3) + j;
        afr[u] = f2bf(P[(k * D + d) * W + w]);
    }

    // Edge outputs (fp32 exact).
    const int k = tid >> 6;
    const int j = tid & 63;
    if (k >= K) return;
    if (j < PADL) {
        float acc = 0.0f;
        for (int m = 0; m <= (W - PADL - 1) + j; ++m)
#pragma unroll
            for (int d = 0; d < D; ++d)
                acc = fmaf(x[d * L + m], P[(k * D + d) * W + m], acc);
        out[k * L + j] = acc;
    } else if (j < 2 * PADL + 1) {
        const int jj = j - PADL;
        float acc = 0.0f;
        for (int m = jj + 1; m < W; ++m)
#pragma unroll
            for (int d = 0; d < D; ++d)
                acc = fmaf(x[d * L + (L - W) + m], P[(k * D + d) * W + m], acc);
        out[k * L + PADL + NMID + jj] = acc;
    }
}

extern "C" void kernel_launch(void* const* d_in, const int* in_sizes, int n_in,
                              void* d_out, int out_size, void* d_ws, size_t ws_size,
                              hipStream_t stream)
{
    const float* x = (const float*)d_in[0];   // (D, L)
    const float* P = (const float*)d_in[1];   // (K, D, W)
    float* out = (float*)d_out;
    unsigned short* afr = (unsigned short*)d_ws;   // 8192 bf16 = 16 KB

    hipLaunchKernelGGL(fullscan_prep, dim3(1), dim3(512), 0, stream, x, P, afr, out);
    hipLaunchKernelGGL(fullscan_mid, dim3(NBLK), dim3(TPB), 0, stream, x, afr, out);
}

// Round 3
// 141.016 us; speedup vs baseline: 2.9152x; 1.4739x over previous
//
#include <hip/hip_runtime.h>

// FullScan via bf16 MFMA 32x32x16, full-M packing.
// out[k,t] = sum_{d<16,w<64} x[d,t+w]*P[k,d,w], K=8, L=1e6.
// M=32 rows = (k, tap-group g): row m = k + 8g, group g covers taps [16g,16g+16).
//   D_g[k](s) = sum_{c<16,d} P[k,d,16g+c] x[d,s+c]
//   out[k,t]  = sum_g D_g[k](t + 16g)   (combine with 16-position shifts)
// Chunk c: reduction index r = d (16 d for tap 16g+c).
// Lane l: n=l&31 (position), h=l>>5. B frag elem j: r=8h+j -> 8 contiguous d
//   -> one aligned ds_read_b128 from d-major xs[pos][16] (half-swizzled).
// C/D: col=lane&31, row=(reg&3)+8*(reg>>2)+4*h  => reg kk+4g holds
//   D_g[k=kk+4h](base+n).  Shift-combine via __shfl_xor(...,16).

constexpr int D    = 16;
constexpr int L    = 1000000;
constexpr int W    = 64;
constexpr int K    = 8;
constexpr int PADL = 31;
constexpr int NMID = L - W + 1;          // 999937
constexpr int TPB  = 256;                // 4 waves
constexpr int OTW  = 12;                 // out 32-pos tiles per wave
constexpr int CTW  = OTW + 2;            // computed tiles per wave (overlap 2)
constexpr int BLK_OUT = 4 * OTW * 32;    // 1536 positions per block
constexpr int XS   = 1632;               // staged positions (need 1615)
constexpr int NBLK = (NMID + BLK_OUT - 1) / BLK_OUT;   // 652
constexpr int NGRID = NBLK + K;          // +8 edge blocks

typedef __attribute__((ext_vector_type(8)))  short short8;
typedef __attribute__((ext_vector_type(16))) float floatx16;

__device__ __forceinline__ unsigned short f2bf(float f) {
    union { float f; unsigned u; } v; v.f = f;
    unsigned u = v.u + 0x7fff + ((v.u >> 16) & 1);   // RNE
    return (unsigned short)(u >> 16);
}

__global__ __launch_bounds__(TPB, 2) void fullscan_mid(
    const float* __restrict__ x, const float* __restrict__ P,
    const unsigned short* __restrict__ afr, float* __restrict__ out)
{
    __shared__ __align__(16) unsigned short xs[XS * 16];   // 52224 B
    const int bid = blockIdx.x;
    const int tid = threadIdx.x;

    if (bid >= NBLK) {
        // Edge block: k = bid - NBLK, 63 outputs (fp32 exact).
        const int k = bid - NBLK;
        const int j = tid;
        if (j < PADL) {
            float acc = 0.0f;
            for (int m = 0; m <= 32 + j; ++m)
#pragma unroll
                for (int d = 0; d < D; ++d)
                    acc = fmaf(x[d * L + m], P[(k * D + d) * W + m], acc);
            out[k * L + j] = acc;
        } else if (j < 2 * PADL + 1) {
            const int jj = j - PADL;                  // 0..31
            float acc = 0.0f;
            for (int m = jj + 1; m < W; ++m)
#pragma unroll
                for (int d = 0; d < D; ++d)
                    acc = fmaf(x[d * L + (L - W) + m], P[(k * D + d) * W + m], acc);
            out[k * L + PADL + NMID + jj] = acc;
        }
        return;
    }

    const int s0   = bid * BLK_OUT;
    const int lane = tid & 63;
    const int wv   = tid >> 6;

    // Resident A fragments: 16 chunks x 4 VGPRs, coalesced from prep table.
    short8 A[16];
#pragma unroll
    for (int c = 0; c < 16; ++c)
        A[c] = *(const short8*)(afr + (c * 64 + lane) * 8);

    // Stage x: thread (pl, dq) loads 4 d-rows at one position, packs to bf16,
    // one ds_write_b64. Half-swizzle on (pos>>2)&1 spreads write banks.
    {
        const int pl = tid & 63;
        const int dq = tid >> 6;            // d-quad 0..3
        const float* xr0 = x + (4 * dq + 0) * L + s0;
        const float* xr1 = x + (4 * dq + 1) * L + s0;
        const float* xr2 = x + (4 * dq + 2) * L + s0;
        const float* xr3 = x + (4 * dq + 3) * L + s0;
#pragma unroll 1
        for (int b = 0; b < XS; b += 64) {
            const int pos = b + pl;
            if (pos < XS) {
                const bool ok = (s0 + pos) < L;
                const float v0 = ok ? xr0[pos] : 0.0f;
                const float v1 = ok ? xr1[pos] : 0.0f;
                const float v2 = ok ? xr2[pos] : 0.0f;
                const float v3 = ok ? xr3[pos] : 0.0f;
                unsigned long long w =
                    (unsigned long long)f2bf(v0)
                  | ((unsigned long long)f2bf(v1) << 16)
                  | ((unsigned long long)f2bf(v2) << 32)
                  | ((unsigned long long)f2bf(v3) << 48);
                const int swz = (pos >> 2) & 1;
                *(unsigned long long*)&xs[pos * 16 + ((dq * 4) ^ (swz * 8))] = w;
            }
        }
    }
    __syncthreads();

    const int n  = lane & 31;
    const int h  = lane >> 5;
    const int hb = h * 8;
    const int wbase = wv * OTW;             // first local out-tile of this wave

    floatx16 accW[3];

#pragma unroll
    for (int jj = 0; jj < CTW; ++jj) {
        floatx16 acc;
#pragma unroll
        for (int r = 0; r < 16; ++r) acc[r] = 0.0f;
        const int p0 = (wbase + jj) * 32 + n;
#pragma unroll
        for (int c = 0; c < 16; ++c) {
            const int pos = c + p0;
            const short8 B = *(const short8*)
                &xs[pos * 16 + (hb ^ (((pos >> 2) & 1) * 8))];
            acc = __builtin_amdgcn_mfma_f32_32x32x16_bf16(A[c], B, acc, 0, 0, 0);
        }
        accW[jj % 3] = acc;

        if (jj >= 2) {
            const int ot = jj - 2;
            const floatx16 a0 = accW[(jj - 2) % 3];   // tile ot
            const floatx16 a1 = accW[(jj - 1) % 3];   // tile ot+1
            const floatx16 a2 = accW[jj % 3];         // tile ot+2
            const int t = s0 + (wbase + ot) * 32 + n;
#pragma unroll
            for (int kk = 0; kk < 4; ++kk) {
                const float g1t = (n >= 16) ? a0[kk + 4]  : a1[kk + 4];
                const float g3t = (n >= 16) ? a1[kk + 12] : a2[kk + 12];
                const float v = a0[kk] + a1[kk + 8]
                              + __shfl_xor(g1t, 16, 64)
                              + __shfl_xor(g3t, 16, 64);
                if (t < NMID)
                    out[(kk + 4 * h) * L + PADL + t] = v;
            }
        }
    }
}

// Prep: A-fragment table only. afr[c][lane][j] = bf16(P[k, d, w]),
// m=lane&31, h=lane>>5, k=m&7, g=m>>3, d=8h+j, w=16g+c.
__global__ void fullscan_prep(const float* __restrict__ P,
                              unsigned short* __restrict__ afr)
{
    const int u = blockIdx.x * 256 + threadIdx.x;   // 32 blocks x 256 = 8192
    const int c = u >> 9, lane = (u >> 3) & 63, j = u & 7;
    const int m = lane & 31, h = lane >> 5;
    const int k = m & 7, g = m >> 3;
    const int d = 8 * h + j;
    const int w = 16 * g + c;
    afr[u] = f2bf(P[(k * D + d) * W + w]);
}

extern "C" void kernel_launch(void* const* d_in, const int* in_sizes, int n_in,
                              void* d_out, int out_size, void* d_ws, size_t ws_size,
                              hipStream_t stream)
{
    const float* x = (const float*)d_in[0];   // (D, L)
    const float* P = (const float*)d_in[1];   // (K, D, W)
    float* out = (float*)d_out;
    unsigned short* afr = (unsigned short*)d_ws;   // 16 KB

    hipLaunchKernelGGL(fullscan_prep, dim3(32), dim3(256), 0, stream, P, afr);
    hipLaunchKernelGGL(fullscan_mid, dim3(NGRID), dim3(TPB), 0, stream,
                       x, P, afr, out);
}

// Round 4
// 139.136 us; speedup vs baseline: 2.9545x; 1.0135x over previous
//
#include <hip/hip_runtime.h>

// FullScan via bf16 MFMA 32x32x16, full-M packing.
// out[k,t] = sum_{d<16,w<64} x[d,t+w]*P[k,d,w], K=8, L=1e6.
// M=32 rows = (k, tap-group g): row m = k + 8g (g covers taps [16g,16g+16)).
//   D_g[k](s) = sum_{c<16,d} P[k,d,16g+c] x[d,s+c]
//   out[k,t]  = sum_g D_g[k](t + 16g)
// Chunk c: reduction r = d. Lane l: n=l&31, h=l>>5; B frag elem j: r=8h+j ->
// 8 contiguous d -> aligned ds_read_b128 from d-major xs[pos][16] (swizzled).
// C/D: col=lane&31, row=(reg&3)+8*(reg>>2)+4h => reg kk+4g = D_g[kk+4h](n).
// R4: OTW 12->8 (LDS 52->35 KB, 3 blocks/CU), grid 652->977 (5% tail),
//     launch_bounds(256,3), explicit B prefetch in chunk loop.

constexpr int D    = 16;
constexpr int L    = 1000000;
constexpr int W    = 64;
constexpr int K    = 8;
constexpr int PADL = 31;
constexpr int NMID = L - W + 1;          // 999937
constexpr int TPB  = 256;                // 4 waves
constexpr int OTW  = 8;                  // out 32-pos tiles per wave
constexpr int CTW  = OTW + 2;            // computed tiles per wave
constexpr int BLK_OUT = 4 * OTW * 32;    // 1024 positions per block
constexpr int XS   = 1104;               // staged positions (need 1103)
constexpr int NBLK = (NMID + BLK_OUT - 1) / BLK_OUT;   // 977
constexpr int NGRID = NBLK + K;          // +8 edge blocks

typedef __attribute__((ext_vector_type(8)))  short short8;
typedef __attribute__((ext_vector_type(16))) float floatx16;

__device__ __forceinline__ unsigned short f2bf(float f) {
    union { float f; unsigned u; } v; v.f = f;
    unsigned u = v.u + 0x7fff + ((v.u >> 16) & 1);   // RNE
    return (unsigned short)(u >> 16);
}

__global__ __launch_bounds__(TPB, 3) void fullscan_mid(
    const float* __restrict__ x, const float* __restrict__ P,
    const unsigned short* __restrict__ afr, float* __restrict__ out)
{
    __shared__ __align__(16) unsigned short xs[XS * 16];   // 35328 B
    const int bid = blockIdx.x;
    const int tid = threadIdx.x;

    if (bid >= NBLK) {
        // Edge block: k = bid - NBLK, 63 outputs (fp32 exact).
        const int k = bid - NBLK;
        const int j = tid;
        if (j < PADL) {
            float acc = 0.0f;
            for (int m = 0; m <= 32 + j; ++m)
#pragma unroll
                for (int d = 0; d < D; ++d)
                    acc = fmaf(x[d * L + m], P[(k * D + d) * W + m], acc);
            out[k * L + j] = acc;
        } else if (j < 2 * PADL + 1) {
            const int jj = j - PADL;                  // 0..31
            float acc = 0.0f;
            for (int m = jj + 1; m < W; ++m)
#pragma unroll
                for (int d = 0; d < D; ++d)
                    acc = fmaf(x[d * L + (L - W) + m], P[(k * D + d) * W + m], acc);
            out[k * L + PADL + NMID + jj] = acc;
        }
        return;
    }

    const int s0   = bid * BLK_OUT;
    const int lane = tid & 63;
    const int wv   = tid >> 6;

    // Resident A fragments: 16 chunks x 4 regs, coalesced from prep table.
    short8 A[16];
#pragma unroll
    for (int c = 0; c < 16; ++c)
        A[c] = *(const short8*)(afr + (c * 64 + lane) * 8);

    // Stage x: thread (pl, dq) loads 4 d-rows at one position, packs to bf16,
    // one ds_write_b64. Half-swizzle on (pos>>2)&1 spreads read banks.
    {
        const int pl = tid & 63;
        const int dq = tid >> 6;            // d-quad 0..3
        const float* xr0 = x + (4 * dq + 0) * L + s0;
        const float* xr1 = x + (4 * dq + 1) * L + s0;
        const float* xr2 = x + (4 * dq + 2) * L + s0;
        const float* xr3 = x + (4 * dq + 3) * L + s0;
#pragma unroll 1
        for (int b = 0; b < XS; b += 64) {
            const int pos = b + pl;
            if (pos < XS) {
                const bool ok = (s0 + pos) < L;
                const float v0 = ok ? xr0[pos] : 0.0f;
                const float v1 = ok ? xr1[pos] : 0.0f;
                const float v2 = ok ? xr2[pos] : 0.0f;
                const float v3 = ok ? xr3[pos] : 0.0f;
                unsigned long long w =
                    (unsigned long long)f2bf(v0)
                  | ((unsigned long long)f2bf(v1) << 16)
                  | ((unsigned long long)f2bf(v2) << 32)
                  | ((unsigned long long)f2bf(v3) << 48);
                const int swz = (pos >> 2) & 1;
                *(unsigned long long*)&xs[pos * 16 + ((dq * 4) ^ (swz * 8))] = w;
            }
        }
    }
    __syncthreads();

    const int n  = lane & 31;
    const int h  = lane >> 5;
    const int hb = h * 8;
    const int wbase = wv * OTW;             // first local out-tile of this wave

    floatx16 accW[3];

#pragma unroll
    for (int jj = 0; jj < CTW; ++jj) {
        floatx16 acc;
#pragma unroll
        for (int r = 0; r < 16; ++r) acc[r] = 0.0f;
        const int p0 = (wbase + jj) * 32 + n;

        // Software-pipelined chunk loop: prefetch B for c+1 before MFMA c.
        short8 Bc = *(const short8*)
            &xs[p0 * 16 + (hb ^ (((p0 >> 2) & 1) * 8))];
#pragma unroll
        for (int c = 0; c < 16; ++c) {
            short8 Bn = Bc;
            if (c < 15) {
                const int pos = p0 + c + 1;
                Bn = *(const short8*)
                    &xs[pos * 16 + (hb ^ (((pos >> 2) & 1) * 8))];
            }
            acc = __builtin_amdgcn_mfma_f32_32x32x16_bf16(A[c], Bc, acc, 0, 0, 0);
            Bc = Bn;
        }
        accW[jj % 3] = acc;

        if (jj >= 2) {
            const int ot = jj - 2;
            const floatx16 a0 = accW[(jj - 2) % 3];   // tile ot
            const floatx16 a1 = accW[(jj - 1) % 3];   // tile ot+1
            const floatx16 a2 = accW[jj % 3];         // tile ot+2
            const int t = s0 + (wbase + ot) * 32 + n;
#pragma unroll
            for (int kk = 0; kk < 4; ++kk) {
                const float g1t = (n >= 16) ? a0[kk + 4]  : a1[kk + 4];
                const float g3t = (n >= 16) ? a1[kk + 12] : a2[kk + 12];
                const float v = a0[kk] + a1[kk + 8]
                              + __shfl_xor(g1t, 16, 64)
                              + __shfl_xor(g3t, 16, 64);
                if (t < NMID)
                    out[(kk + 4 * h) * L + PADL + t] = v;
            }
        }
    }
}

// Prep: A-fragment table. afr[c][lane][j] = bf16(P[k, d, w]),
// m=lane&31, h=lane>>5, k=m&7, g=m>>3, d=8h+j, w=16g+c.
__global__ void fullscan_prep(const float* __restrict__ P,
                              unsigned short* __restrict__ afr)
{
    const int u = blockIdx.x * 256 + threadIdx.x;   // 32 blocks x 256 = 8192
    const int c = u >> 9, lane = (u >> 3) & 63, j = u & 7;
    const int m = lane & 31, h = lane >> 5;
    const int k = m & 7, g = m >> 3;
    const int d = 8 * h + j;
    const int w = 16 * g + c;
    afr[u] = f2bf(P[(k * D + d) * W + w]);
}

extern "C" void kernel_launch(void* const* d_in, const int* in_sizes, int n_in,
                              void* d_out, int out_size, void* d_ws, size_t ws_size,
                              hipStream_t stream)
{
    const float* x = (const float*)d_in[0];   // (D, L)
    const float* P = (const float*)d_in[1];   // (K, D, W)
    float* out = (float*)d_out;
    unsigned short* afr = (unsigned short*)d_ws;   // 16 KB

    hipLaunchKernelGGL(fullscan_prep, dim3(32), dim3(256), 0, stream, P, afr);
    hipLaunchKernelGGL(fullscan_mid, dim3(NGRID), dim3(TPB), 0, stream,
                       x, P, afr, out);
}